// Round 1
// baseline (199.883 us; speedup 1.0000x reference)
//
#include <hip/hip_runtime.h>

typedef unsigned short u16;
typedef unsigned int u32;

typedef __bf16 bf16x8 __attribute__((ext_vector_type(8)));
typedef float f32x4 __attribute__((ext_vector_type(4)));

#define OUT_F 4096
#define IN_F 4096
#define M_ROWS 4096              // 2 * 2048
#define NUM_GROUPS ((OUT_F * IN_F) / 32)   // 524288

#define TILE_E (256 * 64)        // u16 elements per LDS tile buffer (32 KB)

// ---------- helpers ----------

__device__ __forceinline__ u16 f2bf(float f) {
    union { float f; u32 u; } c; c.f = f;
    u32 u = c.u;
    u += 0x7fffu + ((u >> 16) & 1u);   // round-to-nearest-even (finite inputs)
    return (u16)(u >> 16);
}

__device__ __forceinline__ u32 pk2(float a, float b) {
    return (u32)f2bf(a) | ((u32)f2bf(b) << 16);
}

// async global -> LDS, 16 bytes per lane (global_load_lds_dwordx4)
__device__ __forceinline__ void async_copy16(const u16* g, u16* l) {
    __builtin_amdgcn_global_load_lds(
        (const __attribute__((address_space(1))) u32*)g,
        (__attribute__((address_space(3))) u32*)l,
        16, 0, 0);
}

// ---------- fused prep (unchanged — ~7 us, not the bottleneck) ----------
__global__ __launch_bounds__(256) void prep_kernel(
        const float* __restrict__ x, const int* __restrict__ q,
        const float* __restrict__ scales,
        u16* __restrict__ W, u16* __restrict__ Xb) {
    int bid = blockIdx.x;
    int tid = threadIdx.x;
    if (bid < 8192) {
        int t = bid * 256 + tid;                 // [0, NUM_TRIPLETS)
        int b0 = q[3 * t];
        int b1 = q[3 * t + 1];
        int b2 = q[3 * t + 2];
        float mv = scales[t >> 2];
        float s = mv * (2.0f / 7.0f);            // w = v*s - mv
        float o = -mv;

        int v0 = b0 & 7;
        int v1 = (b0 >> 3) & 7;
        int v2 = ((b0 >> 6) & 3) | ((b1 & 1) << 2);
        int v3 = (b1 >> 1) & 7;
        int v4 = (b1 >> 4) & 7;
        int v5 = ((b1 >> 7) & 1) | ((b2 & 3) << 1);
        int v6 = (b2 >> 2) & 7;
        int v7 = (b2 >> 5) & 7;
        uint4 w;
        w.x = pk2(fmaf((float)v0, s, o), fmaf((float)v1, s, o));
        w.y = pk2(fmaf((float)v2, s, o), fmaf((float)v3, s, o));
        w.z = pk2(fmaf((float)v4, s, o), fmaf((float)v5, s, o));
        w.w = pk2(fmaf((float)v6, s, o), fmaf((float)v7, s, o));
        ((uint4*)W)[t] = w;
    } else {
        int i = (bid - 8192) * 256 + tid;
        const float4* p = (const float4*)x + (size_t)i * 2;
        float4 u = p[0], v = p[1];
        uint4 w;
        w.x = pk2(u.x, u.y);
        w.y = pk2(u.z, u.w);
        w.z = pk2(v.x, v.y);
        w.w = pk2(v.z, v.w);
        ((uint4*)Xb)[i] = w;
    }
}

// ---------- 256x256 8-phase bf16 GEMM ----------
// C[m][n] = sum_k A[m][k]*B[n][k] + bias[n]
// A: [M_ROWS][IN_F] bf16 (x), B: [OUT_F][IN_F] bf16 (W), both row-major.
//
// Structure (T1+T2+T3+T4+T5 package; 128^2 2-barrier structure capped ~900 TF):
//  - 512 threads = 8 waves (2M x 4N). Per-wave output 128x64, arranged so each
//    wave's rows span BOTH A-halves and cols span BOTH B-halves:
//      rows:  mh*128 + wr*64 + [0,64),  cols: nh*128 + wc*32 + [0,32)
//    => per K-tile 4 quadrant phases (A0,B0)->(A0,B1)->(A1,B1)->(A1,B0),
//    16 MFMA each; half-tile regions retire one phase at a time.
//  - LDS 128 KB: double-buffered 256x64 tiles for A and B. Staged with
//    global_load_lds width=16; chunk-XOR swizzle pc = lc ^ (row&7) applied on
//    the pre-swizzled GLOBAL source (linear LDS dest), same scheme that
//    measured ZERO bank conflicts in the 128^2 kernel.
//  - Raw s_barrier (no __syncthreads -> no compiler vmcnt(0) drain).
//    Counted s_waitcnt vmcnt(6) ONCE per K-tile: 3 half-tiles (6 loads)
//    stay in flight across barriers.
//  - Stage issue schedule (S(t,X) = stage half-tile X of K-tile t):
//      P0: S(t+1,B0)  -> buf[(t+1)&1]  (B0 of t+1; tile t-1 retired B0)
//      P1: S(t+2,A0)  -> buf[t&1]      (A0 retired after P0)
//      P2: S(t+2,B1)  -> buf[t&1]      (B1 retired after P1)
//      P3: S(t+2,A1)  -> buf[t&1]      (A1 retired after P2)
//    vmcnt(6) at P3 => everything through S(t+1,B0) complete => tile t+1
//    fully resident before its first ds_read. Out-of-range tiles clamp
//    (wrap) so vmcnt accounting stays uniform; data lands in retired
//    regions and is never read.
__global__ __launch_bounds__(512, 2) void gemm_bt_kernel(
        const u16* __restrict__ A, const u16* __restrict__ B,
        const float* __restrict__ bias, float* __restrict__ C) {
    __shared__ u16 sA[2 * TILE_E];
    __shared__ u16 sB[2 * TILE_E];

    const int tid = threadIdx.x;
    const int lane = tid & 63;
    const int w = tid >> 6;          // wave 0..7
    const int wr = w >> 2;           // wave row 0..1
    const int wc = w & 3;            // wave col 0..3
    const int ln = lane & 15;
    const int quad = lane >> 4;
    const int lnx = ln & 7;

    // XCD-aware bijective swizzle: 256 blocks, 8 XCDs, 32 contiguous tiles/XCD
    const int lin = blockIdx.x;
    const int wg = (lin & 7) * 32 + (lin >> 3);
    const int mb = (wg >> 4) * 256;   // M tile
    const int nb = (wg & 15) * 256;   // N tile

    // staging geometry: one half-tile = 128 rows x 64 bf16 = 2 passes x
    // 512 threads x 16B. slot s = p*512+tid: row rl = s>>3, phys chunk pc=s&7,
    // logical chunk lc = pc ^ (rl&7)  (rl&7 == row&7 since halves are 128-row)
    int offg[2], offl[2];
#pragma unroll
    for (int p = 0; p < 2; ++p) {
        int s = p * 512 + tid;
        int rl = s >> 3, pc = s & 7;
        int lc = pc ^ (rl & 7);
        offg[p] = rl * IN_F + lc * 8;
        offl[p] = rl * 64 + pc * 8;      // == s*8: lane-contiguous LDS dest
    }
    const u16* baseA = A + (size_t)mb * IN_F;
    const u16* baseB = B + (size_t)nb * IN_F;

    auto STAGE = [&](u16* lbase, const u16* gbase, int ko, int h) {
#pragma unroll
        for (int p = 0; p < 2; ++p)
            async_copy16(gbase + h * (128 * IN_F) + offg[p] + ko,
                         lbase + h * (128 * 64) + offl[p]);
    };

    // fragment read bases (u16 offsets; row stride 64 u16)
    int arow[2][4], brow[2][2], pck[2];
#pragma unroll
    for (int mh = 0; mh < 2; ++mh)
#pragma unroll
        for (int i = 0; i < 4; ++i)
            arow[mh][i] = (mh * 128 + wr * 64 + i * 16 + ln) * 64;
#pragma unroll
    for (int nh = 0; nh < 2; ++nh)
#pragma unroll
        for (int j = 0; j < 2; ++j)
            brow[nh][j] = (nh * 128 + wc * 32 + j * 16 + ln) * 64;
#pragma unroll
    for (int kk = 0; kk < 2; ++kk)
        pck[kk] = ((kk * 4 + quad) ^ lnx) * 8;

    // bias for this thread's 4 output column groups
    float bj[2][2];
#pragma unroll
    for (int nh = 0; nh < 2; ++nh)
#pragma unroll
        for (int j = 0; j < 2; ++j)
            bj[nh][j] = bias[nb + nh * 128 + wc * 32 + j * 16 + ln];

    f32x4 acc[8][4];
#pragma unroll
    for (int i = 0; i < 8; ++i)
#pragma unroll
        for (int j = 0; j < 4; ++j) acc[i][j] = (f32x4)0.0f;

    bf16x8 av[4][2], bv[2][2];

#define LOAD_A(MH) \
    { _Pragma("unroll") for (int i = 0; i < 4; ++i) { \
        _Pragma("unroll") for (int kk = 0; kk < 2; ++kk) { \
            av[i][kk] = *(const bf16x8*)&aRd[arow[MH][i] + pck[kk]]; } } }

#define LOAD_B(NH) \
    { _Pragma("unroll") for (int j = 0; j < 2; ++j) { \
        _Pragma("unroll") for (int kk = 0; kk < 2; ++kk) { \
            bv[j][kk] = *(const bf16x8*)&bRd[brow[NH][j] + pck[kk]]; } } }

#define MFMA_Q(MH, NH) \
    { _Pragma("unroll") for (int i = 0; i < 4; ++i) { \
        _Pragma("unroll") for (int j = 0; j < 2; ++j) { \
            _Pragma("unroll") for (int kk = 0; kk < 2; ++kk) { \
                acc[(MH)*4 + i][(NH)*2 + j] = \
                    __builtin_amdgcn_mfma_f32_16x16x32_bf16( \
                        av[i][kk], bv[j][kk], acc[(MH)*4 + i][(NH)*2 + j], \
                        0, 0, 0); } } } }

#define PHASE_MFMA(MH, NH) \
    __builtin_amdgcn_s_barrier(); \
    asm volatile("s_waitcnt lgkmcnt(0)" ::: "memory"); \
    __builtin_amdgcn_sched_barrier(0); \
    __builtin_amdgcn_s_setprio(1); \
    MFMA_Q(MH, NH); \
    __builtin_amdgcn_s_setprio(0);

    // ---- prologue: tile0 {A0,B1,A1,B0} + tile1 {A0,B1,A1}; vmcnt(6) keeps
    //      tile1's first 3 half-tiles in flight, guarantees tile0 resident.
    STAGE(sA, baseA, 0, 0);                 // t0 A0
    STAGE(sB, baseB, 0, 1);                 // t0 B1
    STAGE(sA, baseA, 0, 1);                 // t0 A1
    STAGE(sB, baseB, 0, 0);                 // t0 B0
    STAGE(sA + TILE_E, baseA, 64, 0);       // t1 A0
    STAGE(sB + TILE_E, baseB, 64, 1);       // t1 B1
    STAGE(sA + TILE_E, baseA, 64, 1);       // t1 A1
    asm volatile("s_waitcnt vmcnt(6)" ::: "memory");
    __builtin_amdgcn_s_barrier();

#pragma unroll 1
    for (int t = 0; t < 64; ++t) {
        const int cur = t & 1;
        u16* aRd = sA + cur * TILE_E;
        u16* bRd = sB + cur * TILE_E;
        u16* aWr = sA + (cur ^ 1) * TILE_E;
        u16* bWr = sB + (cur ^ 1) * TILE_E;
        const int ko1 = ((t + 1) & 63) << 6;
        const int ko2 = ((t + 2) & 63) << 6;
        (void)aWr;

        // P0 — quadrant (A0,B0); issue S(t+1, B0)
        LOAD_A(0); LOAD_B(0);
        STAGE(bWr, baseB, ko1, 0);
        PHASE_MFMA(0, 0);
        __builtin_amdgcn_s_barrier();

        // P1 — quadrant (A0,B1); issue S(t+2, A0) into current buf (A0 retired)
        LOAD_B(1);
        STAGE(aRd, baseA, ko2, 0);
        PHASE_MFMA(0, 1);
        __builtin_amdgcn_s_barrier();

        // P2 — quadrant (A1,B1); issue S(t+2, B1) (B1 retired)
        LOAD_A(1);
        STAGE(bRd, baseB, ko2, 1);
        PHASE_MFMA(1, 1);
        __builtin_amdgcn_s_barrier();

        // P3 — quadrant (A1,B0); issue S(t+2, A1) (A1 retired)
        LOAD_B(0);
        STAGE(aRd, baseA, ko2, 1);
        PHASE_MFMA(1, 0);
        asm volatile("s_waitcnt vmcnt(6)" ::: "memory");
        __builtin_amdgcn_s_barrier();
    }

#undef LOAD_A
#undef LOAD_B
#undef MFMA_Q
#undef PHASE_MFMA

    // drain trailing (clamped) prefetches before LDS teardown / epilogue
    asm volatile("s_waitcnt vmcnt(0)" ::: "memory");

    // ---- epilogue: C[row][col] = acc + bias[col]
#pragma unroll
    for (int ai = 0; ai < 8; ++ai) {
        const int mh = ai >> 2, i = ai & 3;
        const int mrow = mb + mh * 128 + wr * 64 + i * 16 + quad * 4;
#pragma unroll
        for (int j4 = 0; j4 < 4; ++j4) {
            const int nh = j4 >> 1, j = j4 & 1;
            const int col = nb + nh * 128 + wc * 32 + j * 16 + ln;
            float* cp = C + (size_t)mrow * OUT_F + col;
#pragma unroll
            for (int r = 0; r < 4; ++r)
                cp[(size_t)r * OUT_F] = acc[ai][j4][r] + bj[nh][j];
        }
    }
}

extern "C" void kernel_launch(void* const* d_in, const int* in_sizes, int n_in,
                              void* d_out, int out_size, void* d_ws, size_t ws_size,
                              hipStream_t stream) {
    const float* x = (const float*)d_in[0];       // [2,2048,4096] fp32
    const int* wq = (const int*)d_in[1];          // [NUM_GROUPS*12]
    const float* wn = (const float*)d_in[2];      // [NUM_GROUPS]
    const float* bias = (const float*)d_in[3];    // [4096]
    float* out = (float*)d_out;                   // [2,2048,4096] fp32

    u16* Wb = (u16*)d_ws;                         // 32 MB
    u16* Xb = Wb + (size_t)OUT_F * IN_F;          // 32 MB

    prep_kernel<<<16384, 256, 0, stream>>>(x, wq, wn, Wb, Xb);
    gemm_bt_kernel<<<dim3(256), 512, 0, stream>>>(Xb, Wb, bias, out);
}

// Round 2
// 140.781 us; speedup vs baseline: 1.4198x; 1.4198x over previous
//
#include <hip/hip_runtime.h>

typedef unsigned short u16;
typedef unsigned int u32;

typedef __bf16 bf16x8 __attribute__((ext_vector_type(8)));
typedef float f32x4 __attribute__((ext_vector_type(4)));

#define OUT_F 4096
#define IN_F 4096
#define M_ROWS 4096              // 2 * 2048
#define NUM_GROUPS ((OUT_F * IN_F) / 32)   // 524288

#define TILE_E (256 * 64)        // u16 elements per LDS tile buffer (32 KB)

// ---------- helpers ----------

__device__ __forceinline__ u16 f2bf(float f) {
    union { float f; u32 u; } c; c.f = f;
    u32 u = c.u;
    u += 0x7fffu + ((u >> 16) & 1u);   // round-to-nearest-even (finite inputs)
    return (u16)(u >> 16);
}

__device__ __forceinline__ u32 pk2(float a, float b) {
    return (u32)f2bf(a) | ((u32)f2bf(b) << 16);
}

// async global -> LDS, 16 bytes per lane (global_load_lds_dwordx4)
__device__ __forceinline__ void async_copy16(const u16* g, u16* l) {
    __builtin_amdgcn_global_load_lds(
        (const __attribute__((address_space(1))) u32*)g,
        (__attribute__((address_space(3))) u32*)l,
        16, 0, 0);
}

// 32-bit LDS byte address for inline-asm ds_read
__device__ __forceinline__ u32 lds_addr(const u16* p) {
    return (u32)(uintptr_t)(const __attribute__((address_space(3))) u16*)p;
}

// ---------- fused prep (unchanged — ~7 us, not the bottleneck) ----------
__global__ __launch_bounds__(256) void prep_kernel(
        const float* __restrict__ x, const int* __restrict__ q,
        const float* __restrict__ scales,
        u16* __restrict__ W, u16* __restrict__ Xb) {
    int bid = blockIdx.x;
    int tid = threadIdx.x;
    if (bid < 8192) {
        int t = bid * 256 + tid;                 // [0, NUM_TRIPLETS)
        int b0 = q[3 * t];
        int b1 = q[3 * t + 1];
        int b2 = q[3 * t + 2];
        float mv = scales[t >> 2];
        float s = mv * (2.0f / 7.0f);            // w = v*s - mv
        float o = -mv;

        int v0 = b0 & 7;
        int v1 = (b0 >> 3) & 7;
        int v2 = ((b0 >> 6) & 3) | ((b1 & 1) << 2);
        int v3 = (b1 >> 1) & 7;
        int v4 = (b1 >> 4) & 7;
        int v5 = ((b1 >> 7) & 1) | ((b2 & 3) << 1);
        int v6 = (b2 >> 2) & 7;
        int v7 = (b2 >> 5) & 7;
        uint4 w;
        w.x = pk2(fmaf((float)v0, s, o), fmaf((float)v1, s, o));
        w.y = pk2(fmaf((float)v2, s, o), fmaf((float)v3, s, o));
        w.z = pk2(fmaf((float)v4, s, o), fmaf((float)v5, s, o));
        w.w = pk2(fmaf((float)v6, s, o), fmaf((float)v7, s, o));
        ((uint4*)W)[t] = w;
    } else {
        int i = (bid - 8192) * 256 + tid;
        const float4* p = (const float4*)x + (size_t)i * 2;
        float4 u = p[0], v = p[1];
        uint4 w;
        w.x = pk2(u.x, u.y);
        w.y = pk2(u.z, u.w);
        w.z = pk2(v.x, v.y);
        w.w = pk2(v.z, v.w);
        ((uint4*)Xb)[i] = w;
    }
}

// ---------- 256x256 8-phase bf16 GEMM ----------
// C[m][n] = sum_k A[m][k]*B[n][k] + bias[n]
// A: [M_ROWS][IN_F] bf16 (x), B: [OUT_F][IN_F] bf16 (W), both row-major.
//
// R1 post-mortem: same schedule with C++ LDS reads ran at 30% MfmaUtil —
// the waitcnt pass cannot disambiguate global_load_lds(sA) vs ds_read(sA)
// and inserted vmcnt(0) drains every phase; "memory"-clobbered waitcnt asm
// added more. R2 fix: fragment loads are inline-asm ds_read_b128 (invisible
// to the pass), waitcnt asms carry NO memory clobber. Ordering is enforced
// manually: barrier -> lgkmcnt(0) -> sched_barrier(0) -> MFMA (rule 18),
// counted vmcnt(6) once per K-tile (T4).
//
// Region-retirement schedule (unchanged from R1, proven by barrier walk):
//   P0: read A0,B0; stage S(t+1,B0)->buf^1 ; bar; lgkm0; MFMA(A0,B0); bar
//   P1: read B1   ; stage S(t+2,A0)->buf   ; bar; lgkm0; MFMA(A0,B1); bar
//   P2: read A1   ; stage S(t+2,B1)->buf   ; bar; lgkm0; MFMA(A1,B1); bar
//   P3: read B0   ; stage S(t+2,A1)->buf   ; bar; lgkm0; MFMA(A1,B0);
//       vmcnt(6); bar
// vmcnt(6) leaves exactly S(t+2,{A0,B1,A1}) in flight => tile t+1 fully
// resident before iteration t+1 reads it; every staged region was retired
// one-or-more barriers before its overwrite.
__global__ __launch_bounds__(512, 2) void gemm_bt_kernel(
        const u16* __restrict__ A, const u16* __restrict__ B,
        const float* __restrict__ bias, float* __restrict__ C) {
    __shared__ u16 sA[2 * TILE_E];
    __shared__ u16 sB[2 * TILE_E];

    const int tid = threadIdx.x;
    const int lane = tid & 63;
    const int w = tid >> 6;          // wave 0..7
    const int wr = w >> 2;           // wave row 0..1
    const int wc = w & 3;            // wave col 0..3
    const int ln = lane & 15;
    const int quad = lane >> 4;
    const int lnx = ln & 7;

    // XCD-aware bijective swizzle: 256 blocks, 8 XCDs, 32 contiguous tiles/XCD
    const int lin = blockIdx.x;
    const int wg = (lin & 7) * 32 + (lin >> 3);
    const int mb = (wg >> 4) * 256;   // M tile
    const int nb = (wg & 15) * 256;   // N tile

    // staging geometry: one half-tile = 128 rows x 64 bf16 = 2 passes x
    // 512 threads x 16B. slot s = p*512+tid: row rl = s>>3, phys chunk pc=s&7,
    // logical chunk lc = pc ^ (rl&7)
    int offg[2], offl[2];
#pragma unroll
    for (int p = 0; p < 2; ++p) {
        int s = p * 512 + tid;
        int rl = s >> 3, pc = s & 7;
        int lc = pc ^ (rl & 7);
        offg[p] = rl * IN_F + lc * 8;
        offl[p] = rl * 64 + pc * 8;      // == s*8: lane-contiguous LDS dest
    }
    const u16* baseA = A + (size_t)mb * IN_F;
    const u16* baseB = B + (size_t)nb * IN_F;

    auto STAGE = [&](u16* lbase, const u16* gbase, int ko, int h) {
#pragma unroll
        for (int p = 0; p < 2; ++p)
            async_copy16(gbase + h * (128 * IN_F) + offg[p] + ko,
                         lbase + h * (128 * 64) + offl[p]);
    };

    // fragment LDS byte offsets within a tile buffer (u16 idx * 2)
    int arow[2][4], brow[2][2], pck[2];
#pragma unroll
    for (int mh = 0; mh < 2; ++mh)
#pragma unroll
        for (int i = 0; i < 4; ++i)
            arow[mh][i] = (mh * 128 + wr * 64 + i * 16 + ln) * 64;
#pragma unroll
    for (int nh = 0; nh < 2; ++nh)
#pragma unroll
        for (int j = 0; j < 2; ++j)
            brow[nh][j] = (nh * 128 + wc * 32 + j * 16 + ln) * 64;
#pragma unroll
    for (int kk = 0; kk < 2; ++kk)
        pck[kk] = ((kk * 4 + quad) ^ lnx) * 8;

    u32 aoff[2][4][2], boff[2][2][2];
#pragma unroll
    for (int mh = 0; mh < 2; ++mh)
#pragma unroll
        for (int i = 0; i < 4; ++i)
#pragma unroll
            for (int kk = 0; kk < 2; ++kk)
                aoff[mh][i][kk] = (u32)((arow[mh][i] + pck[kk]) * 2);
#pragma unroll
    for (int nh = 0; nh < 2; ++nh)
#pragma unroll
        for (int j = 0; j < 2; ++j)
#pragma unroll
            for (int kk = 0; kk < 2; ++kk)
                boff[nh][j][kk] = (u32)((brow[nh][j] + pck[kk]) * 2);

    const u32 sAb = lds_addr(sA);
    const u32 sBb = lds_addr(sB);

    // bias for this thread's 4 output column groups
    float bj[2][2];
#pragma unroll
    for (int nh = 0; nh < 2; ++nh)
#pragma unroll
        for (int j = 0; j < 2; ++j)
            bj[nh][j] = bias[nb + nh * 128 + wc * 32 + j * 16 + ln];

    f32x4 acc[8][4];
#pragma unroll
    for (int i = 0; i < 8; ++i)
#pragma unroll
        for (int j = 0; j < 4; ++j) acc[i][j] = (f32x4)0.0f;

    bf16x8 av[4][2], bv[2][2];

// inline-asm LDS reads: invisible to SIInsertWaitcnts -> no auto vmcnt(0)
// drain against in-flight global_load_lds. Manual fences provide ordering.
#define LOAD_A(MH) \
    { _Pragma("unroll") for (int i = 0; i < 4; ++i) { \
        _Pragma("unroll") for (int kk = 0; kk < 2; ++kk) { \
            asm volatile("ds_read_b128 %0, %1" \
                         : "=v"(av[i][kk]) \
                         : "v"(aCur + aoff[MH][i][kk])); } } }

#define LOAD_B(NH) \
    { _Pragma("unroll") for (int j = 0; j < 2; ++j) { \
        _Pragma("unroll") for (int kk = 0; kk < 2; ++kk) { \
            asm volatile("ds_read_b128 %0, %1" \
                         : "=v"(bv[j][kk]) \
                         : "v"(bCur + boff[NH][j][kk])); } } }

#define MFMA_Q(MH, NH) \
    { _Pragma("unroll") for (int i = 0; i < 4; ++i) { \
        _Pragma("unroll") for (int j = 0; j < 2; ++j) { \
            _Pragma("unroll") for (int kk = 0; kk < 2; ++kk) { \
                acc[(MH)*4 + i][(NH)*2 + j] = \
                    __builtin_amdgcn_mfma_f32_16x16x32_bf16( \
                        av[i][kk], bv[j][kk], acc[(MH)*4 + i][(NH)*2 + j], \
                        0, 0, 0); } } } }

#define PHASE_MFMA(MH, NH) \
    __builtin_amdgcn_s_barrier(); \
    asm volatile("s_waitcnt lgkmcnt(0)"); \
    __builtin_amdgcn_sched_barrier(0); \
    __builtin_amdgcn_s_setprio(1); \
    MFMA_Q(MH, NH); \
    __builtin_amdgcn_s_setprio(0); \
    __builtin_amdgcn_sched_barrier(0);

    // ---- prologue: tile0 {A0,B1,A1,B0} + tile1 {A0,B1,A1}; vmcnt(6) keeps
    //      tile1's first 3 half-tiles in flight, guarantees tile0 resident.
    STAGE(sA, baseA, 0, 0);                 // t0 A0
    STAGE(sB, baseB, 0, 1);                 // t0 B1
    STAGE(sA, baseA, 0, 1);                 // t0 A1
    STAGE(sB, baseB, 0, 0);                 // t0 B0
    STAGE(sA + TILE_E, baseA, 64, 0);       // t1 A0
    STAGE(sB + TILE_E, baseB, 64, 1);       // t1 B1
    STAGE(sA + TILE_E, baseA, 64, 1);       // t1 A1
    asm volatile("s_waitcnt vmcnt(6)");
    __builtin_amdgcn_s_barrier();

#pragma unroll 1
    for (int t = 0; t < 64; ++t) {
        const int cur = t & 1;
        const u32 aCur = sAb + (u32)(cur * (TILE_E * 2));
        const u32 bCur = sBb + (u32)(cur * (TILE_E * 2));
        u16* aRd = sA + cur * TILE_E;
        u16* bRd = sB + cur * TILE_E;
        u16* bWr = sB + (cur ^ 1) * TILE_E;
        const int ko1 = ((t + 1) & 63) << 6;
        const int ko2 = ((t + 2) & 63) << 6;

        // P0 — quadrant (A0,B0); issue S(t+1, B0)
        LOAD_A(0); LOAD_B(0);
        STAGE(bWr, baseB, ko1, 0);
        PHASE_MFMA(0, 0);
        __builtin_amdgcn_s_barrier();

        // P1 — quadrant (A0,B1); issue S(t+2, A0) into current buf (A0 retired)
        LOAD_B(1);
        STAGE(aRd, baseA, ko2, 0);
        PHASE_MFMA(0, 1);
        __builtin_amdgcn_s_barrier();

        // P2 — quadrant (A1,B1); issue S(t+2, B1) (B1 retired)
        LOAD_A(1);
        STAGE(bRd, baseB, ko2, 1);
        PHASE_MFMA(1, 1);
        __builtin_amdgcn_s_barrier();

        // P3 — quadrant (A1,B0); issue S(t+2, A1) (A1 retired)
        LOAD_B(0);
        STAGE(aRd, baseA, ko2, 1);
        PHASE_MFMA(1, 0);
        asm volatile("s_waitcnt vmcnt(6)");
        __builtin_amdgcn_s_barrier();
    }

#undef LOAD_A
#undef LOAD_B
#undef MFMA_Q
#undef PHASE_MFMA

    // drain trailing (clamped) prefetches before epilogue
    asm volatile("s_waitcnt vmcnt(0)");

    // ---- epilogue: C[row][col] = acc + bias[col]
#pragma unroll
    for (int ai = 0; ai < 8; ++ai) {
        const int mh = ai >> 2, i = ai & 3;
        const int mrow = mb + mh * 128 + wr * 64 + i * 16 + quad * 4;
#pragma unroll
        for (int j4 = 0; j4 < 4; ++j4) {
            const int nh = j4 >> 1, j = j4 & 1;
            const int col = nb + nh * 128 + wc * 32 + j * 16 + ln;
            float* cp = C + (size_t)mrow * OUT_F + col;
#pragma unroll
            for (int r = 0; r < 4; ++r)
                cp[(size_t)r * OUT_F] = acc[ai][j4][r] + bj[nh][j];
        }
    }
}

extern "C" void kernel_launch(void* const* d_in, const int* in_sizes, int n_in,
                              void* d_out, int out_size, void* d_ws, size_t ws_size,
                              hipStream_t stream) {
    const float* x = (const float*)d_in[0];       // [2,2048,4096] fp32
    const int* wq = (const int*)d_in[1];          // [NUM_GROUPS*12]
    const float* wn = (const float*)d_in[2];      // [NUM_GROUPS]
    const float* bias = (const float*)d_in[3];    // [4096]
    float* out = (float*)d_out;                   // [2,2048,4096] fp32

    u16* Wb = (u16*)d_ws;                         // 32 MB
    u16* Xb = Wb + (size_t)OUT_F * IN_F;          // 32 MB

    prep_kernel<<<16384, 256, 0, stream>>>(x, wq, wn, Wb, Xb);
    gemm_bt_kernel<<<dim3(256), 512, 0, stream>>>(Xb, Wb, bias, out);
}

// Round 4
// 135.076 us; speedup vs baseline: 1.4798x; 1.0422x over previous
//
#include <hip/hip_runtime.h>

typedef unsigned short u16;
typedef unsigned int u32;

typedef __bf16 bf16x8 __attribute__((ext_vector_type(8)));
typedef float f32x4 __attribute__((ext_vector_type(4)));

#define OUT_F 4096
#define IN_F 4096
#define M_ROWS 4096              // 2 * 2048
#define NUM_GROUPS ((OUT_F * IN_F) / 32)   // 524288

#define TILE_E (256 * 64)        // u16 elements per LDS tile buffer (32 KB)

// ---------- helpers ----------

__device__ __forceinline__ u16 f2bf(float f) {
    union { float f; u32 u; } c; c.f = f;
    u32 u = c.u;
    u += 0x7fffu + ((u >> 16) & 1u);   // round-to-nearest-even (finite inputs)
    return (u16)(u >> 16);
}

__device__ __forceinline__ u32 pk2(float a, float b) {
    return (u32)f2bf(a) | ((u32)f2bf(b) << 16);
}

// async global -> LDS, 16 bytes per lane (global_load_lds_dwordx4)
__device__ __forceinline__ void async_copy16(const u16* g, u16* l) {
    __builtin_amdgcn_global_load_lds(
        (const __attribute__((address_space(1))) u32*)g,
        (__attribute__((address_space(3))) u32*)l,
        16, 0, 0);
}

// 32-bit LDS byte address for inline-asm ds_read
__device__ __forceinline__ u32 lds_addr(const u16* p) {
    return (u32)(uintptr_t)(const __attribute__((address_space(3))) u16*)p;
}

// ---------- fused prep (unchanged — not the bottleneck) ----------
__global__ __launch_bounds__(256) void prep_kernel(
        const float* __restrict__ x, const int* __restrict__ q,
        const float* __restrict__ scales,
        u16* __restrict__ W, u16* __restrict__ Xb) {
    int bid = blockIdx.x;
    int tid = threadIdx.x;
    if (bid < 8192) {
        int t = bid * 256 + tid;                 // [0, NUM_TRIPLETS)
        int b0 = q[3 * t];
        int b1 = q[3 * t + 1];
        int b2 = q[3 * t + 2];
        float mv = scales[t >> 2];
        float s = mv * (2.0f / 7.0f);            // w = v*s - mv
        float o = -mv;

        int v0 = b0 & 7;
        int v1 = (b0 >> 3) & 7;
        int v2 = ((b0 >> 6) & 3) | ((b1 & 1) << 2);
        int v3 = (b1 >> 1) & 7;
        int v4 = (b1 >> 4) & 7;
        int v5 = ((b1 >> 7) & 1) | ((b2 & 3) << 1);
        int v6 = (b2 >> 2) & 7;
        int v7 = (b2 >> 5) & 7;
        uint4 w;
        w.x = pk2(fmaf((float)v0, s, o), fmaf((float)v1, s, o));
        w.y = pk2(fmaf((float)v2, s, o), fmaf((float)v3, s, o));
        w.z = pk2(fmaf((float)v4, s, o), fmaf((float)v5, s, o));
        w.w = pk2(fmaf((float)v6, s, o), fmaf((float)v7, s, o));
        ((uint4*)W)[t] = w;
    } else {
        int i = (bid - 8192) * 256 + tid;
        const float4* p = (const float4*)x + (size_t)i * 2;
        float4 u = p[0], v = p[1];
        uint4 w;
        w.x = pk2(u.x, u.y);
        w.y = pk2(u.z, u.w);
        w.z = pk2(v.x, v.y);
        w.w = pk2(v.z, v.w);
        ((uint4*)Xb)[i] = w;
    }
}

// ---------- 256x256 4-phase bf16 GEMM with counted-lgkm pipeline ----------
// C[m][n] = sum_k A[m][k]*B[n][k] + bias[n]
//
// R3 post-mortem (NaN): double-buffer read stride was cur<<16 (65536 B) but
// one tile buffer is TILE_E*2 = 32768 B — odd-tile ds_reads ran past sA into
// sB garbage. R4 fix: curOff = cur<<15. Schedule unchanged:
//  - counted lgkm chains: reads issued in consumption order, lgkmcnt(10/8/6/4)
//    interleaved with 4-MFMA groups; tails (incl. next phase's B-frags) drain
//    under MFMA. DS completes in-order per wave.
//  - B0 held in bv0 across P0..P3, B1 in bv1 (24 reads/wave/tile, not 28).
//  - ONE barrier per phase (ledger: every region's reads lgkm-complete before
//    that wave's barrier arrival; overwriting STAGE issues >=1 barrier later;
//    cross-tile residency via per-tile vmcnt(6)+barrier).
// Stage schedule (proven R2): P0: S(t+1,B0)->buf^1; P1: S(t+2,A0)->buf;
// P2: S(t+2,B1)->buf; P3: S(t+2,A1)->buf; vmcnt(6) at P3 leaves exactly
// S(t+2,{A0,B1,A1}) in flight => tile t+1 fully resident at t+1's P0.
__global__ __launch_bounds__(512, 2) void gemm_bt_kernel(
        const u16* __restrict__ A, const u16* __restrict__ B,
        const float* __restrict__ bias, float* __restrict__ C) {
    __shared__ u16 sA[2 * TILE_E];
    __shared__ u16 sB[2 * TILE_E];

    const int tid = threadIdx.x;
    const int lane = tid & 63;
    const int w = tid >> 6;          // wave 0..7
    const int wr = w >> 2;           // wave row 0..1
    const int wc = w & 3;            // wave col 0..3
    const int ln = lane & 15;
    const int quad = lane >> 4;
    const int lnx = ln & 7;

    // XCD-aware bijective swizzle: 256 blocks, 8 XCDs, 32 contiguous tiles/XCD
    const int lin = blockIdx.x;
    const int wg = (lin & 7) * 32 + (lin >> 3);
    const int mb = (wg >> 4) * 256;   // M tile
    const int nb = (wg & 15) * 256;   // N tile

    // staging geometry: half-tile = 128 rows x 64 bf16 = 2 x 512thr x 16B
    int offg[2], offl[2];
#pragma unroll
    for (int p = 0; p < 2; ++p) {
        int s = p * 512 + tid;
        int rl = s >> 3, pc = s & 7;
        int lc = pc ^ (rl & 7);          // XOR swizzle on global source
        offg[p] = rl * IN_F + lc * 8;
        offl[p] = rl * 64 + pc * 8;      // lane-contiguous LDS dest
    }
    const u16* baseA = A + (size_t)mb * IN_F;
    const u16* baseB = B + (size_t)nb * IN_F;

    auto STAGE = [&](u16* lbase, const u16* gbase, int ko, int h) {
#pragma unroll
        for (int p = 0; p < 2; ++p)
            async_copy16(gbase + h * (128 * IN_F) + offg[p] + ko,
                         lbase + h * (128 * 64) + offl[p]);
    };

    // ds_read base addresses (bytes). Fragment byte offset decomposition:
    //   A: mh*16384 + wr*8192 + i*2048 + ln*128 + ((kk*4+quad)^lnx)*16
    //   B: nh*16384 + wc*4096 + j*2048 + ln*128 + ((kk*4+quad)^lnx)*16
    // mh/nh and i/j terms go in the ds_read offset: immediate; kk picks base.
    const u32 sAb = lds_addr(sA);
    const u32 sBb = lds_addr(sB);
    const u32 aB0 = sAb + (u32)(wr * 8192 + ln * 128 + ((quad ^ lnx) * 16));
    const u32 aB1 = sAb + (u32)(wr * 8192 + ln * 128 + (((4 + quad) ^ lnx) * 16));
    const u32 bB0 = sBb + (u32)(wc * 4096 + ln * 128 + ((quad ^ lnx) * 16));
    const u32 bB1 = sBb + (u32)(wc * 4096 + ln * 128 + (((4 + quad) ^ lnx) * 16));

    // bias for this thread's 4 output column groups
    float bj[2][2];
#pragma unroll
    for (int nh = 0; nh < 2; ++nh)
#pragma unroll
        for (int j = 0; j < 2; ++j)
            bj[nh][j] = bias[nb + nh * 128 + wc * 32 + j * 16 + ln];

    f32x4 acc[8][4];
#pragma unroll
    for (int i = 0; i < 8; ++i)
#pragma unroll
        for (int j = 0; j < 4; ++j) acc[i][j] = (f32x4)0.0f;

    bf16x8 av[4][2];      // current A half fragments (A0 in P0/P1, A1 in P2/P3)
    bf16x8 bv0[2][2];     // B0 fragments, live P0..P3
    bf16x8 bv1[2][2];     // B1 fragments, live P1..P2

#define DSR(dst, base, IMM) \
    asm volatile("ds_read_b128 %0, %1 offset:" #IMM \
                 : "=v"(dst) : "v"(base))

#define WAITG(N) \
    asm volatile("s_waitcnt lgkmcnt(" #N ")"); \
    __builtin_amdgcn_sched_barrier(0);

// 4 MFMAs: av[AI] x BV -> acc[ACR][J0], acc[ACR][J1]
#define MG(AI, ACR, J0, J1, BV) \
    acc[ACR][J0] = __builtin_amdgcn_mfma_f32_16x16x32_bf16( \
        av[AI][0], BV[0][0], acc[ACR][J0], 0, 0, 0); \
    acc[ACR][J0] = __builtin_amdgcn_mfma_f32_16x16x32_bf16( \
        av[AI][1], BV[0][1], acc[ACR][J0], 0, 0, 0); \
    acc[ACR][J1] = __builtin_amdgcn_mfma_f32_16x16x32_bf16( \
        av[AI][0], BV[1][0], acc[ACR][J1], 0, 0, 0); \
    acc[ACR][J1] = __builtin_amdgcn_mfma_f32_16x16x32_bf16( \
        av[AI][1], BV[1][1], acc[ACR][J1], 0, 0, 0);

    // ---- prologue: tile0 {A0,B1,A1,B0} + tile1 {A0,B1,A1}; vmcnt(6) ----
    STAGE(sA, baseA, 0, 0);                 // t0 A0
    STAGE(sB, baseB, 0, 1);                 // t0 B1
    STAGE(sA, baseA, 0, 1);                 // t0 A1
    STAGE(sB, baseB, 0, 0);                 // t0 B0
    STAGE(sA + TILE_E, baseA, 64, 0);       // t1 A0
    STAGE(sB + TILE_E, baseB, 64, 1);       // t1 B1
    STAGE(sA + TILE_E, baseA, 64, 1);       // t1 A1
    asm volatile("s_waitcnt vmcnt(6)");
    __builtin_amdgcn_s_barrier();

#pragma unroll 1
    for (int t = 0; t < 64; ++t) {
        const int cur = t & 1;
        const u32 curOff = (u32)cur << 15;       // cur * 32768 B = TILE_E*2
        const u32 aC0 = aB0 + curOff, aC1 = aB1 + curOff;
        const u32 bC0 = bB0 + curOff, bC1 = bB1 + curOff;
        u16* aRd = sA + cur * TILE_E;
        u16* bRd = sB + cur * TILE_E;
        u16* bWr = sB + (cur ^ 1) * TILE_E;
        const int ko1 = ((t + 1) & 63) << 6;
        const int ko2 = ((t + 2) & 63) << 6;

        // ---- P0: quadrant (A0,B0); stage S(t+1,B0) ----
        STAGE(bWr, baseB, ko1, 0);
        // chain: bv0(4), av=A0(8), bv1(4)  [issue order == wait order]
        DSR(bv0[0][0], bC0, 0);      DSR(bv0[0][1], bC1, 0);
        DSR(bv0[1][0], bC0, 2048);   DSR(bv0[1][1], bC1, 2048);
        DSR(av[0][0], aC0, 0);       DSR(av[0][1], aC1, 0);
        DSR(av[1][0], aC0, 2048);    DSR(av[1][1], aC1, 2048);
        DSR(av[2][0], aC0, 4096);    DSR(av[2][1], aC1, 4096);
        DSR(av[3][0], aC0, 6144);    DSR(av[3][1], aC1, 6144);
        DSR(bv1[0][0], bC0, 16384);  DSR(bv1[0][1], bC1, 16384);
        DSR(bv1[1][0], bC0, 18432);  DSR(bv1[1][1], bC1, 18432);
        __builtin_amdgcn_s_setprio(1);
        WAITG(10); MG(0, 0, 0, 1, bv0);
        WAITG(8);  MG(1, 1, 0, 1, bv0);
        WAITG(6);  MG(2, 2, 0, 1, bv0);
        WAITG(4);  MG(3, 3, 0, 1, bv0);
        __builtin_amdgcn_sched_barrier(0);
        __builtin_amdgcn_s_setprio(0);
        __builtin_amdgcn_s_barrier();

        // ---- P1: quadrant (A0,B1); stage S(t+2,A0) ----
        STAGE(aRd, baseA, ko2, 0);
        __builtin_amdgcn_s_setprio(1);
        WAITG(0);                       // bv1 complete (likely drained)
        MG(0, 0, 2, 3, bv1);
        MG(1, 1, 2, 3, bv1);
        MG(2, 2, 2, 3, bv1);
        MG(3, 3, 2, 3, bv1);
        __builtin_amdgcn_sched_barrier(0);
        __builtin_amdgcn_s_setprio(0);
        __builtin_amdgcn_s_barrier();

        // ---- P2: quadrant (A1,B1); stage S(t+2,B1) ----
        STAGE(bRd, baseB, ko2, 1);
        DSR(av[0][0], aC0, 16384);   DSR(av[0][1], aC1, 16384);
        DSR(av[1][0], aC0, 18432);   DSR(av[1][1], aC1, 18432);
        DSR(av[2][0], aC0, 20480);   DSR(av[2][1], aC1, 20480);
        DSR(av[3][0], aC0, 22528);   DSR(av[3][1], aC1, 22528);
        __builtin_amdgcn_s_setprio(1);
        WAITG(6); MG(0, 4, 2, 3, bv1);
        WAITG(4); MG(1, 5, 2, 3, bv1);
        WAITG(2); MG(2, 6, 2, 3, bv1);
        WAITG(0); MG(3, 7, 2, 3, bv1);
        __builtin_amdgcn_sched_barrier(0);
        __builtin_amdgcn_s_setprio(0);
        __builtin_amdgcn_s_barrier();

        // ---- P3: quadrant (A1,B0); stage S(t+2,A1); vmcnt(6) ----
        STAGE(aRd, baseA, ko2, 1);
        __builtin_amdgcn_s_setprio(1);
        MG(0, 4, 0, 1, bv0);
        MG(1, 5, 0, 1, bv0);
        MG(2, 6, 0, 1, bv0);
        MG(3, 7, 0, 1, bv0);
        __builtin_amdgcn_sched_barrier(0);
        __builtin_amdgcn_s_setprio(0);
        asm volatile("s_waitcnt vmcnt(6)");
        __builtin_amdgcn_s_barrier();
    }

#undef DSR
#undef WAITG
#undef MG

    // drain trailing (wrapped) prefetches before epilogue
    asm volatile("s_waitcnt vmcnt(0)");

    // ---- epilogue: C[row][col] = acc + bias[col]
#pragma unroll
    for (int ai = 0; ai < 8; ++ai) {
        const int mh = ai >> 2, i = ai & 3;
        const int mrow = mb + mh * 128 + wr * 64 + i * 16 + quad * 4;
#pragma unroll
        for (int j4 = 0; j4 < 4; ++j4) {
            const int nh = j4 >> 1, j = j4 & 1;
            const int col = nb + nh * 128 + wc * 32 + j * 16 + ln;
            float* cp = C + (size_t)mrow * OUT_F + col;
#pragma unroll
            for (int r = 0; r < 4; ++r)
                cp[(size_t)r * OUT_F] = acc[ai][j4][r] + bj[nh][j];
        }
    }
}

extern "C" void kernel_launch(void* const* d_in, const int* in_sizes, int n_in,
                              void* d_out, int out_size, void* d_ws, size_t ws_size,
                              hipStream_t stream) {
    const float* x = (const float*)d_in[0];       // [2,2048,4096] fp32
    const int* wq = (const int*)d_in[1];          // [NUM_GROUPS*12]
    const float* wn = (const float*)d_in[2];      // [NUM_GROUPS]
    const float* bias = (const float*)d_in[3];    // [4096]
    float* out = (float*)d_out;                   // [2,2048,4096] fp32

    u16* Wb = (u16*)d_ws;                         // 32 MB
    u16* Xb = Wb + (size_t)OUT_F * IN_F;          // 32 MB

    prep_kernel<<<16384, 256, 0, stream>>>(x, wq, wn, Wb, Xb);
    gemm_bt_kernel<<<dim3(256), 512, 0, stream>>>(Xb, Wb, bias, out);
}